// Round 3
// baseline (977.101 us; speedup 1.0000x reference)
//
#include <hip/hip_runtime.h>
#include <math.h>

#define L 8
#define GPITCH 132   // LDS pitch for fp32 A-tile

typedef unsigned int  u32;
typedef unsigned short u16;

// fp32 -> bf16 round-to-nearest-even
__device__ inline u16 f2bf(float x) {
    u32 u = __float_as_uint(x);
    return (u16)((u + 0x7fffu + ((u >> 16) & 1u)) >> 16);
}
// unpack 2 packed bf16 (low = even elem, high = odd elem)
__device__ inline float2 bf2f2(u32 v) {
    float2 r;
    r.x = __uint_as_float(v << 16);
    r.y = __uint_as_float(v & 0xffff0000u);
    return r;
}
__device__ inline float gelu_t(float x) {
    return 0.5f * x * (1.0f + tanhf(0.7978845608028654f *
           (x + 0.044715f * x * x * x)));
}

// ---------------------------------------------------------------------------
// Fold weights (transposed stores):
//  0: wkaT = (Wk1 . Watt1)^T   1: wvmT = (Wv1 . Wmsg1)^T   2: wqT = Wq0^T
//  3: w1T  = (Wout0 . lin_w)^T 4: lwT  = lin_w^T
// ---------------------------------------------------------------------------
__global__ __launch_bounds__(256) void fold_weights(
    const float* __restrict__ Wk1, const float* __restrict__ Wq0,
    const float* __restrict__ Wv1, const float* __restrict__ Watt1,
    const float* __restrict__ Wmsg1, const float* __restrict__ Wout0,
    const float* __restrict__ lin_w,
    float* __restrict__ wkaT, float* __restrict__ wvmT,
    float* __restrict__ wqT, float* __restrict__ w1T, float* __restrict__ lwT)
{
    int id = blockIdx.x * 256 + threadIdx.x;   // < 5*16384
    int which = id >> 14;
    int idx = id & 16383;
    int col = idx & 127;
    int k = idx >> 7;
    if (which == 0) {
        int h = col >> 5, f = col & 31;
        float s = 0.f;
        for (int d = 0; d < 32; ++d)
            s += Wk1[k * 128 + h * 32 + d] * Watt1[h * 1024 + d * 32 + f];
        wkaT[col * 128 + k] = s;
    } else if (which == 1) {
        int h = col >> 5, f = col & 31;
        float s = 0.f;
        for (int d = 0; d < 32; ++d)
            s += Wv1[k * 128 + h * 32 + d] * Wmsg1[h * 1024 + d * 32 + f];
        wvmT[col * 128 + k] = s;
    } else if (which == 2) {
        wqT[col * 128 + k] = Wq0[k * 128 + col];
    } else if (which == 3) {
        float s = 0.f;
        for (int d = 0; d < 128; ++d)
            s += Wout0[k * 128 + d] * lin_w[d * 128 + col];
        w1T[col * 128 + k] = s;
    } else {
        lwT[col * 128 + k] = lin_w[k * 128 + col];
    }
}

// ---------------------------------------------------------------------------
// Fused encode + projection GEMM.
// Stages the ENCODED node tile (embedding gather + mean pool + relu) straight
// into LDS (emb is 5 MB -> L2-resident), optionally writes x to global (f32,
// needed later for the skip path), then runs 1 or 2 weight passes off the
// same tile, emitting bf16.
// ---------------------------------------------------------------------------
__global__ __launch_bounds__(256) void gemm_enc(
    const int* __restrict__ tok, const float* __restrict__ emb,
    const float* __restrict__ WT0, const float* __restrict__ WT1,
    float* __restrict__ xout, u16* __restrict__ Y0, u16* __restrict__ Y1,
    int N)
{
    __shared__ float sa[128 * GPITCH];
    int tid = threadIdx.x;
    int tx = tid & 15, ty = tid >> 4;
    int rbase = blockIdx.x * 128;

    for (int idx = tid; idx < 128 * 128; idx += 256) {
        int r = idx >> 7, k = idx & 127;
        int row = rbase + r;
        float v = 0.f;
        if (row < N) {
            float acc = 0.f; int cnt = 0;
#pragma unroll
            for (int l = 0; l < L; ++l) {
                int t = tok[row * L + l];
                if (t != 0) { cnt++; acc += emb[(size_t)t * 128 + k]; }
            }
            v = fmaxf(acc / fmaxf((float)cnt, 1.0f), 0.f);
            if (xout) xout[(size_t)row * 128 + k] = v;
        }
        sa[r * GPITCH + k] = v;
    }
    __syncthreads();

    for (int pass = 0; pass < 2; ++pass) {
        const float* WT = pass ? WT1 : WT0;
        u16* Y = pass ? Y1 : Y0;
        if (WT == nullptr) break;
        float acc[8][8];
#pragma unroll
        for (int i = 0; i < 8; ++i)
#pragma unroll
            for (int j = 0; j < 8; ++j) acc[i][j] = 0.f;

        for (int k0 = 0; k0 < 128; k0 += 4) {
            float xf[8][4];
#pragma unroll
            for (int i = 0; i < 8; ++i) {
                float4 t = *(const float4*)&sa[(ty + 16 * i) * GPITCH + k0];
                xf[i][0] = t.x; xf[i][1] = t.y; xf[i][2] = t.z; xf[i][3] = t.w;
            }
            float wf[8][4];
#pragma unroll
            for (int j = 0; j < 8; ++j) {
                float4 t = *(const float4*)&WT[(size_t)(tx + 16 * j) * 128 + k0];
                wf[j][0] = t.x; wf[j][1] = t.y; wf[j][2] = t.z; wf[j][3] = t.w;
            }
#pragma unroll
            for (int kk = 0; kk < 4; ++kk)
#pragma unroll
                for (int i = 0; i < 8; ++i)
#pragma unroll
                    for (int j = 0; j < 8; ++j)
                        acc[i][j] += xf[i][kk] * wf[j][kk];
        }
#pragma unroll
        for (int i = 0; i < 8; ++i) {
            int row = rbase + ty + 16 * i;
            if (row < N) {
#pragma unroll
                for (int j = 0; j < 8; ++j)
                    Y[(size_t)row * 128 + tx + 16 * j] = f2bf(acc[i][j]);
            }
        }
    }
}

// ---------------------------------------------------------------------------
// Output GEMM: out = A0(bf16) @ WT0 + A1(f32) @ WT1 + bias   (f32 out)
// ---------------------------------------------------------------------------
__global__ __launch_bounds__(256) void gemm_out(
    const u16* __restrict__ A0, const float* __restrict__ WT0,
    const float* __restrict__ A1, const float* __restrict__ WT1,
    const float* __restrict__ bias, float* __restrict__ Y, int N)
{
    __shared__ float sa[128 * GPITCH];
    int tid = threadIdx.x;
    int tx = tid & 15, ty = tid >> 4;
    int rbase = blockIdx.x * 128;

    float acc[8][8];
#pragma unroll
    for (int i = 0; i < 8; ++i)
#pragma unroll
        for (int j = 0; j < 8; ++j) acc[i][j] = 0.f;

    for (int pass = 0; pass < 2; ++pass) {
        const float* WT = pass ? WT1 : WT0;
        if (pass) __syncthreads();
        for (int idx = tid; idx < 128 * 128; idx += 256) {
            int r = idx >> 7, k = idx & 127;
            int row = rbase + r;
            float v = 0.f;
            if (row < N) {
                if (pass == 0) {
                    u16 uv = A0[(size_t)row * 128 + k];
                    v = __uint_as_float(((u32)uv) << 16);
                } else {
                    v = A1[(size_t)row * 128 + k];
                }
            }
            sa[r * GPITCH + k] = v;
        }
        __syncthreads();

        for (int k0 = 0; k0 < 128; k0 += 4) {
            float xf[8][4];
#pragma unroll
            for (int i = 0; i < 8; ++i) {
                float4 t = *(const float4*)&sa[(ty + 16 * i) * GPITCH + k0];
                xf[i][0] = t.x; xf[i][1] = t.y; xf[i][2] = t.z; xf[i][3] = t.w;
            }
            float wf[8][4];
#pragma unroll
            for (int j = 0; j < 8; ++j) {
                float4 t = *(const float4*)&WT[(size_t)(tx + 16 * j) * 128 + k0];
                wf[j][0] = t.x; wf[j][1] = t.y; wf[j][2] = t.z; wf[j][3] = t.w;
            }
#pragma unroll
            for (int kk = 0; kk < 4; ++kk)
#pragma unroll
                for (int i = 0; i < 8; ++i)
#pragma unroll
                    for (int j = 0; j < 8; ++j)
                        acc[i][j] += xf[i][kk] * wf[j][kk];
        }
    }

#pragma unroll
    for (int i = 0; i < 8; ++i) {
        int row = rbase + ty + 16 * i;
        if (row < N) {
#pragma unroll
            for (int j = 0; j < 8; ++j) {
                int c = tx + 16 * j;
                Y[(size_t)row * 128 + c] = acc[i][j] + bias[c];
            }
        }
    }
}

// ---------------------------------------------------------------------------
// CSR build: degree histogram -> single-block scan -> scatter (src-sorted by dst)
// ---------------------------------------------------------------------------
__global__ __launch_bounds__(256) void edge_hist(
    const int* __restrict__ dstI, int* __restrict__ deg, int E)
{
    int e = blockIdx.x * 256 + threadIdx.x;
    if (e < E) atomicAdd(&deg[dstI[e]], 1);
}

__global__ __launch_bounds__(1024) void scan_deg(
    const int* __restrict__ deg, int* __restrict__ rowptr,
    int* __restrict__ cursor, int Na)
{
    __shared__ int part[1024];
    int tid = threadIdx.x;
    int chunk = (Na + 1023) >> 10;
    int base = tid * chunk;
    int s = 0;
    for (int j = 0; j < chunk; ++j) {
        int i = base + j;
        if (i < Na) s += deg[i];
    }
    part[tid] = s;
    __syncthreads();
    for (int off = 1; off < 1024; off <<= 1) {
        int v = 0;
        if (tid >= off) v = part[tid - off];
        __syncthreads();
        if (tid >= off) part[tid] += v;
        __syncthreads();
    }
    int run = part[tid] - s;   // exclusive start of this thread's chunk
    for (int j = 0; j < chunk; ++j) {
        int i = base + j;
        if (i < Na) {
            rowptr[i] = run;
            cursor[i] = run;
            run += deg[i];
        }
    }
    if (tid == 1023) rowptr[Na] = part[1023];
}

__global__ __launch_bounds__(256) void edge_scatter(
    const int* __restrict__ srcI, const int* __restrict__ dstI,
    int* __restrict__ cursor, int* __restrict__ csrc, int E)
{
    int e = blockIdx.x * 256 + threadIdx.x;
    if (e < E) {
        int pos = atomicAdd(&cursor[dstI[e]], 1);
        csrc[pos] = srcI[e];
    }
}

// ---------------------------------------------------------------------------
// CSR aggregation: one wave per destination node. Walks the node's edge list
// (2-way unrolled for MLP), computes softmax numerator/denominator entirely
// in registers, then ONE 256 B store of gelu(agg/denom) as bf16.
// No atomics, no intermediate edge tensors.
// lane -> elems {2l, 2l+1}; head h = lane>>4; 16-lane xor-reduce per score.
// ---------------------------------------------------------------------------
__global__ __launch_bounds__(256) void csr_agg(
    const u32* __restrict__ ktp, const u32* __restrict__ qap,
    const u32* __restrict__ mtp, const int* __restrict__ rowptr,
    const int* __restrict__ csrc, const float* __restrict__ mu1,
    u32* __restrict__ gagg, int Na)
{
    int dst = blockIdx.x * 4 + (threadIdx.x >> 6);
    if (dst >= Na) return;
    int lane = threadIdx.x & 63;
    int h = lane >> 4;
    float muh = mu1[h] * 0.17677669529663689f;  // mu/sqrt(32)
    float2 qf = bf2f2(qap[(size_t)dst * 64 + lane]);

    float a0 = 0.f, a1 = 0.f, dsum = 0.f;
    int beg = rowptr[dst], end = rowptr[dst + 1];

    for (int i = beg; i < end; i += 2) {
        int s0 = csrc[i];
        int s1 = (i + 1 < end) ? csrc[i + 1] : -1;
        u32 kv0 = ktp[(size_t)s0 * 64 + lane];
        u32 mv0 = mtp[(size_t)s0 * 64 + lane];
        u32 kv1 = 0, mv1 = 0;
        if (s1 >= 0) {
            kv1 = ktp[(size_t)s1 * 64 + lane];
            mv1 = mtp[(size_t)s1 * 64 + lane];
        }
        {
            float2 kf = bf2f2(kv0);
            float p = kf.x * qf.x + kf.y * qf.y;
            p += __shfl_xor(p, 1, 16);
            p += __shfl_xor(p, 2, 16);
            p += __shfl_xor(p, 4, 16);
            p += __shfl_xor(p, 8, 16);
            float ev = __expf(p * muh);
            float2 mf = bf2f2(mv0);
            dsum += ev; a0 += ev * mf.x; a1 += ev * mf.y;
        }
        if (s1 >= 0) {
            float2 kf = bf2f2(kv1);
            float p = kf.x * qf.x + kf.y * qf.y;
            p += __shfl_xor(p, 1, 16);
            p += __shfl_xor(p, 2, 16);
            p += __shfl_xor(p, 4, 16);
            p += __shfl_xor(p, 8, 16);
            float ev = __expf(p * muh);
            float2 mf = bf2f2(mv1);
            dsum += ev; a0 += ev * mf.x; a1 += ev * mf.y;
        }
    }
    float dn = dsum + 1e-9f;
    a0 = gelu_t(a0 / dn);
    a1 = gelu_t(a1 / dn);
    gagg[(size_t)dst * 64 + lane] = ((u32)f2bf(a1) << 16) | (u32)f2bf(a0);
}

// ---------------------------------------------------------------------------
extern "C" void kernel_launch(void* const* d_in, const int* in_sizes, int n_in,
                              void* d_out, int out_size, void* d_ws, size_t ws_size,
                              hipStream_t stream)
{
    const int*   tok_a   = (const int*)d_in[0];
    const int*   tok_p   = (const int*)d_in[1];
    const int*   edge_pa = (const int*)d_in[3];
    const float* emb     = (const float*)d_in[4];
    const float* Wk      = (const float*)d_in[5];
    const float* Wq      = (const float*)d_in[6];
    const float* Wv      = (const float*)d_in[7];
    const float* Watt    = (const float*)d_in[8];
    const float* Wmsg    = (const float*)d_in[9];
    const float* mu      = (const float*)d_in[10];
    const float* Wout    = (const float*)d_in[11];
    const float* lin_w   = (const float*)d_in[12];
    const float* lin_b   = (const float*)d_in[13];

    int Na = in_sizes[0] / L;
    int Np = in_sizes[1] / L;
    int E  = in_sizes[3] / 2;
    float* out = (float*)d_out;

    // workspace layout
    float* ws = (float*)d_ws;
    float* xa     = ws;                                  // Na*128 f32
    u16*   qa     = (u16*)(xa + (size_t)Na * 128);       // Na*128 bf16
    u16*   kt     = qa + (size_t)Na * 128;               // Np*128 bf16
    u16*   mt     = kt + (size_t)Np * 128;               // Np*128 bf16
    u16*   gagg   = mt + (size_t)Np * 128;               // Na*128 bf16
    int*   deg    = (int*)(gagg + (size_t)Na * 128);     // Na
    int*   rowptr = deg + Na;                            // Na+1
    int*   cursor = rowptr + Na + 1;                     // Na
    int*   csrc   = cursor + Na;                         // E
    float* wkaT   = (float*)(csrc + E);
    float* wvmT   = wkaT + 16384;
    float* wqT    = wvmT + 16384;
    float* w1T    = wqT + 16384;
    float* lwT    = w1T + 16384;

    const int* e_src = edge_pa;
    const int* e_dst = edge_pa + E;

    // 1) fold weights + CSR build prep (independent of GEMMs)
    hipMemsetAsync(deg, 0, (size_t)Na * sizeof(int), stream);
    fold_weights<<<(5 * 16384) / 256, 256, 0, stream>>>(
        Wk + 16384, Wq, Wv + 16384, Watt + 4096, Wmsg + 4096, Wout, lin_w,
        wkaT, wvmT, wqT, w1T, lwT);

    int egrid = (E + 255) / 256;
    edge_hist<<<egrid, 256, 0, stream>>>(e_dst, deg, E);
    scan_deg<<<1, 1024, 0, stream>>>(deg, rowptr, cursor, Na);
    edge_scatter<<<egrid, 256, 0, stream>>>(e_src, e_dst, cursor, csrc, E);

    // 2) fused encode + projections
    int gba = (Na + 127) / 128;
    int gbp = (Np + 127) / 128;
    gemm_enc<<<gba, 256, 0, stream>>>(tok_a, emb, wqT, nullptr, xa, qa, nullptr, Na);
    gemm_enc<<<gbp, 256, 0, stream>>>(tok_p, emb, wkaT, wvmT, nullptr, kt, mt, Np);

    // 3) CSR aggregation (softmax + weighted sum + normalize + gelu, in regs)
    csr_agg<<<(Na + 3) / 4, 256, 0, stream>>>(
        (const u32*)kt, (const u32*)qa, (const u32*)mt, rowptr, csrc,
        mu + 4, (u32*)gagg, Na);

    // 4) output head: out = gagg @ w1T + xa @ lwT + lin_b
    gemm_out<<<gba, 256, 0, stream>>>(gagg, w1T, xa, lwT, lin_b, out, Na);
}

// Round 4
// 498.713 us; speedup vs baseline: 1.9592x; 1.9592x over previous
//
#include <hip/hip_runtime.h>
#include <math.h>

#define L 8

typedef unsigned int  u32;
typedef unsigned short u16;
typedef __attribute__((ext_vector_type(8))) short bf16x8;
typedef __attribute__((ext_vector_type(4))) float f32x4;

// fp32 -> bf16 round-to-nearest-even
__device__ inline u16 f2bf(float x) {
    u32 u = __float_as_uint(x);
    return (u16)((u + 0x7fffu + ((u >> 16) & 1u)) >> 16);
}
// unpack 2 packed bf16 (low = even elem, high = odd elem)
__device__ inline float2 bf2f2(u32 v) {
    float2 r;
    r.x = __uint_as_float(v << 16);
    r.y = __uint_as_float(v & 0xffff0000u);
    return r;
}
__device__ inline float gelu_t(float x) {
    return 0.5f * x * (1.0f + tanhf(0.7978845608028654f *
           (x + 0.044715f * x * x * x)));
}

// ---------------------------------------------------------------------------
// Fold weights -> bf16, stored transposed (WT[c*128+k] = W[k][c]):
//  0: wkaT = (Wk1 . Watt1)^T   1: wvmT = (Wv1 . Wmsg1)^T   2: wqT = Wq0^T
//  3: w1T  = (Wout0 . lin_w)^T 4: lwT  = lin_w^T
// ---------------------------------------------------------------------------
__global__ __launch_bounds__(256) void fold_weights(
    const float* __restrict__ Wk1, const float* __restrict__ Wq0,
    const float* __restrict__ Wv1, const float* __restrict__ Watt1,
    const float* __restrict__ Wmsg1, const float* __restrict__ Wout0,
    const float* __restrict__ lin_w,
    u16* __restrict__ wkaT, u16* __restrict__ wvmT,
    u16* __restrict__ wqT, u16* __restrict__ w1T, u16* __restrict__ lwT)
{
    int id = blockIdx.x * 256 + threadIdx.x;   // < 5*16384
    int which = id >> 14;
    int idx = id & 16383;
    int col = idx & 127;
    int k = idx >> 7;
    if (which == 0) {
        int h = col >> 5, f = col & 31;
        float s = 0.f;
        for (int d = 0; d < 32; ++d)
            s += Wk1[k * 128 + h * 32 + d] * Watt1[h * 1024 + d * 32 + f];
        wkaT[col * 128 + k] = f2bf(s);
    } else if (which == 1) {
        int h = col >> 5, f = col & 31;
        float s = 0.f;
        for (int d = 0; d < 32; ++d)
            s += Wv1[k * 128 + h * 32 + d] * Wmsg1[h * 1024 + d * 32 + f];
        wvmT[col * 128 + k] = f2bf(s);
    } else if (which == 2) {
        wqT[col * 128 + k] = f2bf(Wq0[k * 128 + col]);
    } else if (which == 3) {
        float s = 0.f;
        for (int d = 0; d < 128; ++d)
            s += Wout0[k * 128 + d] * lin_w[d * 128 + col];
        w1T[col * 128 + k] = f2bf(s);
    } else {
        lwT[col * 128 + k] = f2bf(lin_w[k * 128 + col]);
    }
}

// ---------------------------------------------------------------------------
// Node encoder: embedding lookup, pad-masked mean pool, relu -> bf16.
// Thread per (node, d); massive grid so gather latency hides under TLP.
// ---------------------------------------------------------------------------
__global__ __launch_bounds__(256) void encode_nodes(
    const int* __restrict__ tok, const float* __restrict__ emb,
    u16* __restrict__ x, int N)
{
    int i = blockIdx.x * 256 + threadIdx.x;
    if (i >= N * 128) return;
    int n = i >> 7, d = i & 127;
    float acc = 0.f;
    int cnt = 0;
#pragma unroll
    for (int l = 0; l < L; ++l) {
        int t = tok[n * L + l];
        if (t != 0) { cnt++; acc += emb[(size_t)t * 128 + d]; }
    }
    float dn = fmaxf((float)cnt, 1.0f);
    x[i] = f2bf(fmaxf(acc / dn, 0.f));
}

// ---------------------------------------------------------------------------
// MFMA projection GEMM: Y = A[N,128](bf16) @ W (1 or 2 weights), bf16 out.
// Block = 4 waves; wave w owns rows [blk*64 + w*16, +16), all 128 cols.
// No LDS: A-frag = 16B contiguous (row=l&15, k=(l>>4)*8+j); B-frag = 16B from
// WT[col][k] (col=l&15). W is 32KB, L2-broadcast across blocks.
// D layout: col=lane&15, row=(lane>>4)*4+reg (verified m89/m91).
// ---------------------------------------------------------------------------
__global__ __launch_bounds__(256) void mfma_proj(
    const u16* __restrict__ A, const u16* __restrict__ WT0,
    const u16* __restrict__ WT1, u16* __restrict__ Y0, u16* __restrict__ Y1,
    int N)
{
    int wave = threadIdx.x >> 6;
    int l = threadIdx.x & 63;
    int rbase = blockIdx.x * 64 + wave * 16;
    int arow = rbase + (l & 15);
    if (arow >= N) arow = N - 1;      // clamp; stores are guarded
    int kb = (l >> 4) * 8;

    bf16x8 af[4];
#pragma unroll
    for (int ks = 0; ks < 4; ++ks)
        af[ks] = *(const bf16x8*)(A + (size_t)arow * 128 + ks * 32 + kb);

    for (int w = 0; w < 2; ++w) {
        const u16* WT = w ? WT1 : WT0;
        u16* Y = w ? Y1 : Y0;
        if (!WT) break;
        f32x4 acc[8];
#pragma unroll
        for (int ct = 0; ct < 8; ++ct) acc[ct] = (f32x4){0.f, 0.f, 0.f, 0.f};
#pragma unroll
        for (int ks = 0; ks < 4; ++ks) {
#pragma unroll
            for (int ct = 0; ct < 8; ++ct) {
                bf16x8 bf = *(const bf16x8*)(WT + (size_t)(ct * 16 + (l & 15)) * 128 + ks * 32 + kb);
                acc[ct] = __builtin_amdgcn_mfma_f32_16x16x32_bf16(af[ks], bf, acc[ct], 0, 0, 0);
            }
        }
        int srow = rbase + ((l >> 4) << 2);
#pragma unroll
        for (int ct = 0; ct < 8; ++ct) {
            int col = ct * 16 + (l & 15);
#pragma unroll
            for (int r = 0; r < 4; ++r) {
                if (srow + r < N)
                    Y[(size_t)(srow + r) * 128 + col] = f2bf(acc[ct][r]);
            }
        }
    }
}

// ---------------------------------------------------------------------------
// MFMA output GEMM: out = A0@W0 + A1@W1 + bias  (bf16 in, f32 out)
// ---------------------------------------------------------------------------
__global__ __launch_bounds__(256) void mfma_out(
    const u16* __restrict__ A0, const u16* __restrict__ WT0,
    const u16* __restrict__ A1, const u16* __restrict__ WT1,
    const float* __restrict__ bias, float* __restrict__ Y, int N)
{
    int wave = threadIdx.x >> 6;
    int l = threadIdx.x & 63;
    int rbase = blockIdx.x * 64 + wave * 16;
    int arow = rbase + (l & 15);
    if (arow >= N) arow = N - 1;
    int kb = (l >> 4) * 8;

    f32x4 acc[8];
#pragma unroll
    for (int ct = 0; ct < 8; ++ct) acc[ct] = (f32x4){0.f, 0.f, 0.f, 0.f};

    for (int w = 0; w < 2; ++w) {
        const u16* A  = w ? A1 : A0;
        const u16* WT = w ? WT1 : WT0;
        bf16x8 af[4];
#pragma unroll
        for (int ks = 0; ks < 4; ++ks)
            af[ks] = *(const bf16x8*)(A + (size_t)arow * 128 + ks * 32 + kb);
#pragma unroll
        for (int ks = 0; ks < 4; ++ks) {
#pragma unroll
            for (int ct = 0; ct < 8; ++ct) {
                bf16x8 bf = *(const bf16x8*)(WT + (size_t)(ct * 16 + (l & 15)) * 128 + ks * 32 + kb);
                acc[ct] = __builtin_amdgcn_mfma_f32_16x16x32_bf16(af[ks], bf, acc[ct], 0, 0, 0);
            }
        }
    }
    int srow = rbase + ((l >> 4) << 2);
#pragma unroll
    for (int ct = 0; ct < 8; ++ct) {
        int col = ct * 16 + (l & 15);
        float b = bias[col];
#pragma unroll
        for (int r = 0; r < 4; ++r) {
            if (srow + r < N)
                Y[(size_t)(srow + r) * 128 + col] = acc[ct][r] + b;
        }
    }
}

// ---------------------------------------------------------------------------
// CSR build: degree histogram -> single-block scan -> scatter
// ---------------------------------------------------------------------------
__global__ __launch_bounds__(256) void edge_hist(
    const int* __restrict__ dstI, int* __restrict__ deg, int E)
{
    int e = blockIdx.x * 256 + threadIdx.x;
    if (e < E) atomicAdd(&deg[dstI[e]], 1);
}

__global__ __launch_bounds__(1024) void scan_deg(
    const int* __restrict__ deg, int* __restrict__ rowptr,
    int* __restrict__ cursor, int Na)
{
    __shared__ int part[1024];
    int tid = threadIdx.x;
    int chunk = (Na + 1023) >> 10;
    int base = tid * chunk;
    int s = 0;
    for (int j = 0; j < chunk; ++j) {
        int i = base + j;
        if (i < Na) s += deg[i];
    }
    part[tid] = s;
    __syncthreads();
    for (int off = 1; off < 1024; off <<= 1) {
        int v = 0;
        if (tid >= off) v = part[tid - off];
        __syncthreads();
        if (tid >= off) part[tid] += v;
        __syncthreads();
    }
    int run = part[tid] - s;
    for (int j = 0; j < chunk; ++j) {
        int i = base + j;
        if (i < Na) {
            rowptr[i] = run;
            cursor[i] = run;
            run += deg[i];
        }
    }
    if (tid == 1023) rowptr[Na] = part[1023];
}

__global__ __launch_bounds__(256) void edge_scatter(
    const int* __restrict__ srcI, const int* __restrict__ dstI,
    int* __restrict__ cursor, int* __restrict__ csrc, int E)
{
    int e = blockIdx.x * 256 + threadIdx.x;
    if (e < E) {
        int pos = atomicAdd(&cursor[dstI[e]], 1);
        csrc[pos] = srcI[e];
    }
}

// ---------------------------------------------------------------------------
// CSR aggregation: one wave per destination. Softmax num/denom in registers,
// one 256 B bf16 store per node (normalize + gelu applied here).
// lane -> elems {2l,2l+1}; head h = lane>>4; 16-lane xor-reduce per score.
// ---------------------------------------------------------------------------
__global__ __launch_bounds__(256) void csr_agg(
    const u32* __restrict__ ktp, const u32* __restrict__ qap,
    const u32* __restrict__ mtp, const int* __restrict__ rowptr,
    const int* __restrict__ csrc, const float* __restrict__ mu1,
    u32* __restrict__ gagg, int Na)
{
    int dst = blockIdx.x * 4 + (threadIdx.x >> 6);
    if (dst >= Na) return;
    int lane = threadIdx.x & 63;
    int h = lane >> 4;
    float muh = mu1[h] * 0.17677669529663689f;  // mu/sqrt(32)
    float2 qf = bf2f2(qap[(size_t)dst * 64 + lane]);

    float a0 = 0.f, a1 = 0.f, dsum = 0.f;
    int beg = rowptr[dst], end = rowptr[dst + 1];

    for (int i = beg; i < end; i += 2) {
        int s0 = csrc[i];
        int s1 = (i + 1 < end) ? csrc[i + 1] : -1;
        u32 kv0 = ktp[(size_t)s0 * 64 + lane];
        u32 mv0 = mtp[(size_t)s0 * 64 + lane];
        u32 kv1 = 0, mv1 = 0;
        if (s1 >= 0) {
            kv1 = ktp[(size_t)s1 * 64 + lane];
            mv1 = mtp[(size_t)s1 * 64 + lane];
        }
        {
            float2 kf = bf2f2(kv0);
            float p = kf.x * qf.x + kf.y * qf.y;
            p += __shfl_xor(p, 1, 16);
            p += __shfl_xor(p, 2, 16);
            p += __shfl_xor(p, 4, 16);
            p += __shfl_xor(p, 8, 16);
            float ev = __expf(p * muh);
            float2 mf = bf2f2(mv0);
            dsum += ev; a0 += ev * mf.x; a1 += ev * mf.y;
        }
        if (s1 >= 0) {
            float2 kf = bf2f2(kv1);
            float p = kf.x * qf.x + kf.y * qf.y;
            p += __shfl_xor(p, 1, 16);
            p += __shfl_xor(p, 2, 16);
            p += __shfl_xor(p, 4, 16);
            p += __shfl_xor(p, 8, 16);
            float ev = __expf(p * muh);
            float2 mf = bf2f2(mv1);
            dsum += ev; a0 += ev * mf.x; a1 += ev * mf.y;
        }
    }
    float dn = dsum + 1e-9f;
    a0 = gelu_t(a0 / dn);
    a1 = gelu_t(a1 / dn);
    gagg[(size_t)dst * 64 + lane] = ((u32)f2bf(a1) << 16) | (u32)f2bf(a0);
}

// ---------------------------------------------------------------------------
extern "C" void kernel_launch(void* const* d_in, const int* in_sizes, int n_in,
                              void* d_out, int out_size, void* d_ws, size_t ws_size,
                              hipStream_t stream)
{
    const int*   tok_a   = (const int*)d_in[0];
    const int*   tok_p   = (const int*)d_in[1];
    const int*   edge_pa = (const int*)d_in[3];
    const float* emb     = (const float*)d_in[4];
    const float* Wk      = (const float*)d_in[5];
    const float* Wq      = (const float*)d_in[6];
    const float* Wv      = (const float*)d_in[7];
    const float* Watt    = (const float*)d_in[8];
    const float* Wmsg    = (const float*)d_in[9];
    const float* mu      = (const float*)d_in[10];
    const float* Wout    = (const float*)d_in[11];
    const float* lin_w   = (const float*)d_in[12];
    const float* lin_b   = (const float*)d_in[13];

    int Na = in_sizes[0] / L;
    int Np = in_sizes[1] / L;
    int E  = in_sizes[3] / 2;
    float* out = (float*)d_out;

    // workspace layout (all 4B-aligned: every segment is an even elem count)
    u16* xa     = (u16*)d_ws;                       // Na*128 bf16
    u16* qa     = xa + (size_t)Na * 128;            // Na*128 bf16
    u16* kt     = qa + (size_t)Na * 128;            // Np*128 bf16
    u16* mt     = kt + (size_t)Np * 128;            // Np*128 bf16
    u16* xp     = mt + (size_t)Np * 128;            // Np*128 bf16
    u16* gagg   = xp + (size_t)Np * 128;            // Na*128 bf16
    int* deg    = (int*)(gagg + (size_t)Na * 128);  // Na
    int* rowptr = deg + Na;                         // Na+1 (+1 pad int below)
    int* cursor = rowptr + Na + 2;                  // Na
    int* csrc   = cursor + Na;                      // E
    u16* wkaT   = (u16*)(csrc + E);                 // 16384 bf16 each
    u16* wvmT   = wkaT + 16384;
    u16* wqT    = wvmT + 16384;
    u16* w1T    = wqT + 16384;
    u16* lwT    = w1T + 16384;

    const int* e_src = edge_pa;
    const int* e_dst = edge_pa + E;

    // 1) weight folding + CSR build
    hipMemsetAsync(deg, 0, (size_t)Na * sizeof(int), stream);
    fold_weights<<<(5 * 16384) / 256, 256, 0, stream>>>(
        Wk + 16384, Wq, Wv + 16384, Watt + 4096, Wmsg + 4096, Wout, lin_w,
        wkaT, wvmT, wqT, w1T, lwT);
    int egrid = (E + 255) / 256;
    edge_hist<<<egrid, 256, 0, stream>>>(e_dst, deg, E);
    scan_deg<<<1, 1024, 0, stream>>>(deg, rowptr, cursor, Na);
    edge_scatter<<<egrid, 256, 0, stream>>>(e_src, e_dst, cursor, csrc, E);

    // 2) node encoding (high-occupancy, bf16 out)
    encode_nodes<<<(Na * 128 + 255) / 256, 256, 0, stream>>>(tok_a, emb, xa, Na);
    encode_nodes<<<(Np * 128 + 255) / 256, 256, 0, stream>>>(tok_p, emb, xp, Np);

    // 3) MFMA projections: qa = xa@Wq0; kt = xp@(Wk1*Watt1); mt = xp@(Wv1*Wmsg1)
    int gba = (Na + 63) / 64;
    int gbp = (Np + 63) / 64;
    mfma_proj<<<gba, 256, 0, stream>>>(xa, wqT, nullptr, qa, nullptr, Na);
    mfma_proj<<<gbp, 256, 0, stream>>>(xp, wkaT, wvmT, kt, mt, Np);

    // 4) CSR aggregation (softmax + weighted sum + normalize + gelu)
    csr_agg<<<(Na + 3) / 4, 256, 0, stream>>>(
        (const u32*)kt, (const u32*)qa, (const u32*)mt, rowptr, csrc,
        mu + 4, (u32*)gagg, Na);

    // 5) output head: out = gagg@w1T + xa@lwT + lin_b
    mfma_out<<<gba, 256, 0, stream>>>(gagg, w1T, xa, lwT, lin_b, out, Na);
}

// Round 5
// 383.205 us; speedup vs baseline: 2.5498x; 1.3014x over previous
//
#include <hip/hip_runtime.h>
#include <math.h>

#define L 8

typedef unsigned int  u32;
typedef unsigned short u16;
typedef __attribute__((ext_vector_type(8))) short bf16x8;
typedef __attribute__((ext_vector_type(4))) float f32x4;

// fp32 -> bf16 round-to-nearest-even
__device__ inline u16 f2bf(float x) {
    u32 u = __float_as_uint(x);
    return (u16)((u + 0x7fffu + ((u >> 16) & 1u)) >> 16);
}
// unpack 2 packed bf16 (low = even elem, high = odd elem)
__device__ inline float2 bf2f2(u32 v) {
    float2 r;
    r.x = __uint_as_float(v << 16);
    r.y = __uint_as_float(v & 0xffff0000u);
    return r;
}
__device__ inline float gelu_t(float x) {
    return 0.5f * x * (1.0f + tanhf(0.7978845608028654f *
           (x + 0.044715f * x * x * x)));
}

// ---------------------------------------------------------------------------
// Fold weights -> bf16, stored transposed (WT[c*128+k] = W[k][c]):
//  0: wkaT = (Wk1 . Watt1)^T   1: wvmT = (Wv1 . Wmsg1)^T   2: wqT = Wq0^T
//  3: w1T  = (Wout0 . lin_w)^T 4: lwT  = lin_w^T
// ---------------------------------------------------------------------------
__global__ __launch_bounds__(256) void fold_weights(
    const float* __restrict__ Wk1, const float* __restrict__ Wq0,
    const float* __restrict__ Wv1, const float* __restrict__ Watt1,
    const float* __restrict__ Wmsg1, const float* __restrict__ Wout0,
    const float* __restrict__ lin_w,
    u16* __restrict__ wkaT, u16* __restrict__ wvmT,
    u16* __restrict__ wqT, u16* __restrict__ w1T, u16* __restrict__ lwT)
{
    int id = blockIdx.x * 256 + threadIdx.x;   // < 5*16384
    int which = id >> 14;
    int idx = id & 16383;
    int col = idx & 127;
    int k = idx >> 7;
    if (which == 0) {
        int h = col >> 5, f = col & 31;
        float s = 0.f;
        for (int d = 0; d < 32; ++d)
            s += Wk1[k * 128 + h * 32 + d] * Watt1[h * 1024 + d * 32 + f];
        wkaT[col * 128 + k] = f2bf(s);
    } else if (which == 1) {
        int h = col >> 5, f = col & 31;
        float s = 0.f;
        for (int d = 0; d < 32; ++d)
            s += Wv1[k * 128 + h * 32 + d] * Wmsg1[h * 1024 + d * 32 + f];
        wvmT[col * 128 + k] = f2bf(s);
    } else if (which == 2) {
        wqT[col * 128 + k] = f2bf(Wq0[k * 128 + col]);
    } else if (which == 3) {
        float s = 0.f;
        for (int d = 0; d < 128; ++d)
            s += Wout0[k * 128 + d] * lin_w[d * 128 + col];
        w1T[col * 128 + k] = f2bf(s);
    } else {
        lwT[col * 128 + k] = f2bf(lin_w[k * 128 + col]);
    }
}

// ---------------------------------------------------------------------------
// Node encoder: embedding lookup, pad-masked mean pool, relu -> bf16.
// ---------------------------------------------------------------------------
__global__ __launch_bounds__(256) void encode_nodes(
    const int* __restrict__ tok, const float* __restrict__ emb,
    u16* __restrict__ x, int N)
{
    int i = blockIdx.x * 256 + threadIdx.x;
    if (i >= N * 128) return;
    int n = i >> 7, d = i & 127;
    float acc = 0.f;
    int cnt = 0;
#pragma unroll
    for (int l = 0; l < L; ++l) {
        int t = tok[n * L + l];
        if (t != 0) { cnt++; acc += emb[(size_t)t * 128 + d]; }
    }
    float dn = fmaxf((float)cnt, 1.0f);
    x[i] = f2bf(fmaxf(acc / dn, 0.f));
}

// ---------------------------------------------------------------------------
// MFMA projection GEMM: Y = A[N,128](bf16) @ W (1 or 2 weights), bf16 out.
// ---------------------------------------------------------------------------
__global__ __launch_bounds__(256) void mfma_proj(
    const u16* __restrict__ A, const u16* __restrict__ WT0,
    const u16* __restrict__ WT1, u16* __restrict__ Y0, u16* __restrict__ Y1,
    int N)
{
    int wave = threadIdx.x >> 6;
    int l = threadIdx.x & 63;
    int rbase = blockIdx.x * 64 + wave * 16;
    int arow = rbase + (l & 15);
    if (arow >= N) arow = N - 1;      // clamp; stores are guarded
    int kb = (l >> 4) * 8;

    bf16x8 af[4];
#pragma unroll
    for (int ks = 0; ks < 4; ++ks)
        af[ks] = *(const bf16x8*)(A + (size_t)arow * 128 + ks * 32 + kb);

    for (int w = 0; w < 2; ++w) {
        const u16* WT = w ? WT1 : WT0;
        u16* Y = w ? Y1 : Y0;
        if (!WT) break;
        f32x4 acc[8];
#pragma unroll
        for (int ct = 0; ct < 8; ++ct) acc[ct] = (f32x4){0.f, 0.f, 0.f, 0.f};
#pragma unroll
        for (int ks = 0; ks < 4; ++ks) {
#pragma unroll
            for (int ct = 0; ct < 8; ++ct) {
                bf16x8 bf = *(const bf16x8*)(WT + (size_t)(ct * 16 + (l & 15)) * 128 + ks * 32 + kb);
                acc[ct] = __builtin_amdgcn_mfma_f32_16x16x32_bf16(af[ks], bf, acc[ct], 0, 0, 0);
            }
        }
        int srow = rbase + ((l >> 4) << 2);
#pragma unroll
        for (int ct = 0; ct < 8; ++ct) {
            int col = ct * 16 + (l & 15);
#pragma unroll
            for (int r = 0; r < 4; ++r) {
                if (srow + r < N)
                    Y[(size_t)(srow + r) * 128 + col] = f2bf(acc[ct][r]);
            }
        }
    }
}

// ---------------------------------------------------------------------------
// MFMA output GEMM: out = A0@W0 + A1@W1 + bias  (bf16 in, f32 out)
// ---------------------------------------------------------------------------
__global__ __launch_bounds__(256) void mfma_out(
    const u16* __restrict__ A0, const u16* __restrict__ WT0,
    const u16* __restrict__ A1, const u16* __restrict__ WT1,
    const float* __restrict__ bias, float* __restrict__ Y, int N)
{
    int wave = threadIdx.x >> 6;
    int l = threadIdx.x & 63;
    int rbase = blockIdx.x * 64 + wave * 16;
    int arow = rbase + (l & 15);
    if (arow >= N) arow = N - 1;
    int kb = (l >> 4) * 8;

    f32x4 acc[8];
#pragma unroll
    for (int ct = 0; ct < 8; ++ct) acc[ct] = (f32x4){0.f, 0.f, 0.f, 0.f};

    for (int w = 0; w < 2; ++w) {
        const u16* A  = w ? A1 : A0;
        const u16* WT = w ? WT1 : WT0;
        bf16x8 af[4];
#pragma unroll
        for (int ks = 0; ks < 4; ++ks)
            af[ks] = *(const bf16x8*)(A + (size_t)arow * 128 + ks * 32 + kb);
#pragma unroll
        for (int ks = 0; ks < 4; ++ks) {
#pragma unroll
            for (int ct = 0; ct < 8; ++ct) {
                bf16x8 bf = *(const bf16x8*)(WT + (size_t)(ct * 16 + (l & 15)) * 128 + ks * 32 + kb);
                acc[ct] = __builtin_amdgcn_mfma_f32_16x16x32_bf16(af[ks], bf, acc[ct], 0, 0, 0);
            }
        }
    }
    int srow = rbase + ((l >> 4) << 2);
#pragma unroll
    for (int ct = 0; ct < 8; ++ct) {
        int col = ct * 16 + (l & 15);
        float b = bias[col];
#pragma unroll
        for (int r = 0; r < 4; ++r) {
            if (srow + r < N)
                Y[(size_t)(srow + r) * 128 + col] = acc[ct][r] + b;
        }
    }
}

// ---------------------------------------------------------------------------
// CSR build: histogram -> hierarchical scan (3 kernels) -> scatter
// ---------------------------------------------------------------------------
__global__ __launch_bounds__(256) void edge_hist(
    const int* __restrict__ dstI, int* __restrict__ deg, int E)
{
    int e = blockIdx.x * 256 + threadIdx.x;
    if (e < E) atomicAdd(&deg[dstI[e]], 1);
}

// per-block scan: block handles 1024 elems (thread = 4 contiguous via int4).
// writes per-element LOCAL exclusive prefix + per-block total.
__global__ __launch_bounds__(256) void scan_local(
    const int* __restrict__ deg, int* __restrict__ locpref,
    int* __restrict__ blocksum, int Na)
{
    __shared__ int lds[256];
    int t = threadIdx.x;
    int base = blockIdx.x * 1024 + t * 4;
    int4 v = {0, 0, 0, 0};
    if (base + 3 < Na) {
        v = *(const int4*)(deg + base);
    } else {
        if (base + 0 < Na) v.x = deg[base + 0];
        if (base + 1 < Na) v.y = deg[base + 1];
        if (base + 2 < Na) v.z = deg[base + 2];
        if (base + 3 < Na) v.w = deg[base + 3];
    }
    int tot = v.x + v.y + v.z + v.w;
    lds[t] = tot;
    __syncthreads();
    for (int off = 1; off < 256; off <<= 1) {
        int u = (t >= off) ? lds[t - off] : 0;
        __syncthreads();
        lds[t] += u;
        __syncthreads();
    }
    int excl = lds[t] - tot;
    if (base < Na) {
        int4 o;
        o.x = excl;
        o.y = excl + v.x;
        o.z = o.y + v.y;
        o.w = o.z + v.z;
        if (base + 3 < Na) *(int4*)(locpref + base) = o;
        else {
            locpref[base] = o.x;
            if (base + 1 < Na) locpref[base + 1] = o.y;
            if (base + 2 < Na) locpref[base + 2] = o.z;
        }
    }
    if (t == 255) blocksum[blockIdx.x] = lds[255];
}

// scan the (<=256) block sums; write exclusive block offsets + grand total.
__global__ __launch_bounds__(256) void scan_block(
    const int* __restrict__ blocksum, int* __restrict__ blockoff,
    int* __restrict__ rowptr, int nb, int Na)
{
    __shared__ int lds[256];
    int t = threadIdx.x;
    int s = (t < nb) ? blocksum[t] : 0;
    lds[t] = s;
    __syncthreads();
    for (int off = 1; off < 256; off <<= 1) {
        int u = (t >= off) ? lds[t - off] : 0;
        __syncthreads();
        lds[t] += u;
        __syncthreads();
    }
    if (t < nb) blockoff[t] = lds[t] - s;
    if (t == 255) rowptr[Na] = lds[255];
}

// rowptr[i] = locpref[i] + blockoff[i>>10]; cursor[i] = rowptr[i]
__global__ __launch_bounds__(256) void scan_final(
    const int* __restrict__ locpref, const int* __restrict__ blockoff,
    int* __restrict__ rowptr, int* __restrict__ cursor, int Na)
{
    int i = blockIdx.x * 256 + threadIdx.x;
    if (i < Na) {
        int v = locpref[i] + blockoff[i >> 10];
        rowptr[i] = v;
        cursor[i] = v;
    }
}

__global__ __launch_bounds__(256) void edge_scatter(
    const int* __restrict__ srcI, const int* __restrict__ dstI,
    int* __restrict__ cursor, int* __restrict__ csrc, int E)
{
    int e = blockIdx.x * 256 + threadIdx.x;
    if (e < E) {
        int pos = atomicAdd(&cursor[dstI[e]], 1);
        csrc[pos] = srcI[e];
    }
}

// ---------------------------------------------------------------------------
// CSR aggregation: one wave per destination. Softmax num/denom in registers,
// one 256 B bf16 store per node (normalize + gelu applied here).
// lane -> elems {2l,2l+1}; head h = lane>>4; 16-lane xor-reduce per score.
// ---------------------------------------------------------------------------
__global__ __launch_bounds__(256) void csr_agg(
    const u32* __restrict__ ktp, const u32* __restrict__ qap,
    const u32* __restrict__ mtp, const int* __restrict__ rowptr,
    const int* __restrict__ csrc, const float* __restrict__ mu1,
    u32* __restrict__ gagg, int Na)
{
    int dst = blockIdx.x * 4 + (threadIdx.x >> 6);
    if (dst >= Na) return;
    int lane = threadIdx.x & 63;
    int h = lane >> 4;
    float muh = mu1[h] * 0.17677669529663689f;  // mu/sqrt(32)
    float2 qf = bf2f2(qap[(size_t)dst * 64 + lane]);

    float a0 = 0.f, a1 = 0.f, dsum = 0.f;
    int beg = rowptr[dst], end = rowptr[dst + 1];

    for (int i = beg; i < end; i += 2) {
        int s0 = csrc[i];
        int s1 = (i + 1 < end) ? csrc[i + 1] : -1;
        u32 kv0 = ktp[(size_t)s0 * 64 + lane];
        u32 mv0 = mtp[(size_t)s0 * 64 + lane];
        u32 kv1 = 0, mv1 = 0;
        if (s1 >= 0) {
            kv1 = ktp[(size_t)s1 * 64 + lane];
            mv1 = mtp[(size_t)s1 * 64 + lane];
        }
        {
            float2 kf = bf2f2(kv0);
            float p = kf.x * qf.x + kf.y * qf.y;
            p += __shfl_xor(p, 1, 16);
            p += __shfl_xor(p, 2, 16);
            p += __shfl_xor(p, 4, 16);
            p += __shfl_xor(p, 8, 16);
            float ev = __expf(p * muh);
            float2 mf = bf2f2(mv0);
            dsum += ev; a0 += ev * mf.x; a1 += ev * mf.y;
        }
        if (s1 >= 0) {
            float2 kf = bf2f2(kv1);
            float p = kf.x * qf.x + kf.y * qf.y;
            p += __shfl_xor(p, 1, 16);
            p += __shfl_xor(p, 2, 16);
            p += __shfl_xor(p, 4, 16);
            p += __shfl_xor(p, 8, 16);
            float ev = __expf(p * muh);
            float2 mf = bf2f2(mv1);
            dsum += ev; a0 += ev * mf.x; a1 += ev * mf.y;
        }
    }
    float dn = dsum + 1e-9f;
    a0 = gelu_t(a0 / dn);
    a1 = gelu_t(a1 / dn);
    gagg[(size_t)dst * 64 + lane] = ((u32)f2bf(a1) << 16) | (u32)f2bf(a0);
}

// ---------------------------------------------------------------------------
extern "C" void kernel_launch(void* const* d_in, const int* in_sizes, int n_in,
                              void* d_out, int out_size, void* d_ws, size_t ws_size,
                              hipStream_t stream)
{
    const int*   tok_a   = (const int*)d_in[0];
    const int*   tok_p   = (const int*)d_in[1];
    const int*   edge_pa = (const int*)d_in[3];
    const float* emb     = (const float*)d_in[4];
    const float* Wk      = (const float*)d_in[5];
    const float* Wq      = (const float*)d_in[6];
    const float* Wv      = (const float*)d_in[7];
    const float* Watt    = (const float*)d_in[8];
    const float* Wmsg    = (const float*)d_in[9];
    const float* mu      = (const float*)d_in[10];
    const float* Wout    = (const float*)d_in[11];
    const float* lin_w   = (const float*)d_in[12];
    const float* lin_b   = (const float*)d_in[13];

    int Na = in_sizes[0] / L;
    int Np = in_sizes[1] / L;
    int E  = in_sizes[3] / 2;
    float* out = (float*)d_out;

    // workspace layout (all segments 4B-aligned)
    u16* xa      = (u16*)d_ws;                      // Na*128 bf16
    u16* qa      = xa + (size_t)Na * 128;           // Na*128 bf16
    u16* kt      = qa + (size_t)Na * 128;           // Np*128 bf16
    u16* mt      = kt + (size_t)Np * 128;           // Np*128 bf16
    u16* xp      = mt + (size_t)Np * 128;           // Np*128 bf16
    u16* gagg    = xp + (size_t)Np * 128;           // Na*128 bf16
    int* deg     = (int*)(gagg + (size_t)Na * 128); // Na
    int* locpref = deg + Na;                        // Na
    int* rowptr  = locpref + Na;                    // Na+2
    int* cursor  = rowptr + Na + 2;                 // Na
    int* csrc    = cursor + Na;                     // E
    int* blocksum= csrc + E;                        // 256
    int* blockoff= blocksum + 256;                  // 256
    u16* wkaT    = (u16*)(blockoff + 256);          // 16384 bf16 each
    u16* wvmT    = wkaT + 16384;
    u16* wqT     = wvmT + 16384;
    u16* w1T     = wqT + 16384;
    u16* lwT     = w1T + 16384;

    const int* e_src = edge_pa;
    const int* e_dst = edge_pa + E;

    // 1) weight folding + CSR build
    hipMemsetAsync(deg, 0, (size_t)Na * sizeof(int), stream);
    fold_weights<<<(5 * 16384) / 256, 256, 0, stream>>>(
        Wk + 16384, Wq, Wv + 16384, Watt + 4096, Wmsg + 4096, Wout, lin_w,
        wkaT, wvmT, wqT, w1T, lwT);
    int egrid = (E + 255) / 256;
    edge_hist<<<egrid, 256, 0, stream>>>(e_dst, deg, E);
    int nb = (Na + 1023) / 1024;   // <= 256 (Na <= 262144)
    scan_local<<<nb, 256, 0, stream>>>(deg, locpref, blocksum, Na);
    scan_block<<<1, 256, 0, stream>>>(blocksum, blockoff, rowptr, nb, Na);
    scan_final<<<(Na + 255) / 256, 256, 0, stream>>>(locpref, blockoff, rowptr, cursor, Na);
    edge_scatter<<<egrid, 256, 0, stream>>>(e_src, e_dst, cursor, csrc, E);

    // 2) node encoding (high-occupancy, bf16 out)
    encode_nodes<<<(Na * 128 + 255) / 256, 256, 0, stream>>>(tok_a, emb, xa, Na);
    encode_nodes<<<(Np * 128 + 255) / 256, 256, 0, stream>>>(tok_p, emb, xp, Np);

    // 3) MFMA projections: qa = xa@Wq0; kt = xp@(Wk1*Watt1); mt = xp@(Wv1*Wmsg1)
    int gba = (Na + 63) / 64;
    int gbp = (Np + 63) / 64;
    mfma_proj<<<gba, 256, 0, stream>>>(xa, wqT, nullptr, qa, nullptr, Na);
    mfma_proj<<<gbp, 256, 0, stream>>>(xp, wkaT, wvmT, kt, mt, Np);

    // 4) CSR aggregation (softmax + weighted sum + normalize + gelu)
    csr_agg<<<(Na + 3) / 4, 256, 0, stream>>>(
        (const u32*)kt, (const u32*)qa, (const u32*)mt, rowptr, csrc,
        mu + 4, (u32*)gagg, Na);

    // 5) output head: out = gagg@w1T + xa@lwT + lin_b
    mfma_out<<<gba, 256, 0, stream>>>(gagg, w1T, xa, lwT, lin_b, out, Na);
}

// Round 6
// 315.690 us; speedup vs baseline: 3.0951x; 1.2139x over previous
//
#include <hip/hip_runtime.h>
#include <math.h>

#define L 8

typedef unsigned int  u32;
typedef unsigned short u16;
typedef __attribute__((ext_vector_type(8))) short bf16x8;
typedef __attribute__((ext_vector_type(4))) float f32x4;

// fp32 -> bf16 round-to-nearest-even
__device__ inline u16 f2bf(float x) {
    u32 u = __float_as_uint(x);
    return (u16)((u + 0x7fffu + ((u >> 16) & 1u)) >> 16);
}
// unpack 2 packed bf16 (low = even elem, high = odd elem)
__device__ inline float2 bf2f2(u32 v) {
    float2 r;
    r.x = __uint_as_float(v << 16);
    r.y = __uint_as_float(v & 0xffff0000u);
    return r;
}
__device__ inline float gelu_t(float x) {
    return 0.5f * x * (1.0f + tanhf(0.7978845608028654f *
           (x + 0.044715f * x * x * x)));
}

// ---------------------------------------------------------------------------
// Fold weights -> bf16, stored transposed (WT[c*128+k] = W[k][c]):
//  0: wkaT = (Wk1 . Watt1)^T   1: wvmT = (Wv1 . Wmsg1)^T   2: wqT = Wq0^T
//  3: w1T  = (Wout0 . lin_w)^T 4: lwT  = lin_w^T
// ---------------------------------------------------------------------------
__global__ __launch_bounds__(256) void fold_weights(
    const float* __restrict__ Wk1, const float* __restrict__ Wq0,
    const float* __restrict__ Wv1, const float* __restrict__ Watt1,
    const float* __restrict__ Wmsg1, const float* __restrict__ Wout0,
    const float* __restrict__ lin_w,
    u16* __restrict__ wkaT, u16* __restrict__ wvmT,
    u16* __restrict__ wqT, u16* __restrict__ w1T, u16* __restrict__ lwT)
{
    int id = blockIdx.x * 256 + threadIdx.x;   // < 5*16384
    int which = id >> 14;
    int idx = id & 16383;
    int col = idx & 127;
    int k = idx >> 7;
    if (which == 0) {
        int h = col >> 5, f = col & 31;
        float s = 0.f;
        for (int d = 0; d < 32; ++d)
            s += Wk1[k * 128 + h * 32 + d] * Watt1[h * 1024 + d * 32 + f];
        wkaT[col * 128 + k] = f2bf(s);
    } else if (which == 1) {
        int h = col >> 5, f = col & 31;
        float s = 0.f;
        for (int d = 0; d < 32; ++d)
            s += Wv1[k * 128 + h * 32 + d] * Wmsg1[h * 1024 + d * 32 + f];
        wvmT[col * 128 + k] = f2bf(s);
    } else if (which == 2) {
        wqT[col * 128 + k] = f2bf(Wq0[k * 128 + col]);
    } else if (which == 3) {
        float s = 0.f;
        for (int d = 0; d < 128; ++d)
            s += Wout0[k * 128 + d] * lin_w[d * 128 + col];
        w1T[col * 128 + k] = f2bf(s);
    } else {
        lwT[col * 128 + k] = f2bf(lin_w[k * 128 + col]);
    }
}

// ---------------------------------------------------------------------------
// Merged node encoder (authors + papers in one grid).
// One WAVE per node; lane covers 2 adjacent dims (float2 gather, u32 store).
// ---------------------------------------------------------------------------
__global__ __launch_bounds__(256) void encode_nodes(
    const int* __restrict__ tok_a, const int* __restrict__ tok_p,
    const float* __restrict__ emb,
    u32* __restrict__ xa32, u32* __restrict__ xp32, int Na, int Ntot)
{
    int i = blockIdx.x * 256 + threadIdx.x;
    int n = i >> 6, d2 = i & 63;
    if (n >= Ntot) return;
    const int* tok = (n < Na) ? (tok_a + (size_t)n * L)
                              : (tok_p + (size_t)(n - Na) * L);
    float ax = 0.f, ay = 0.f;
    int cnt = 0;
#pragma unroll
    for (int l = 0; l < L; ++l) {
        int t = tok[l];
        if (t != 0) {
            cnt++;
            float2 e = *(const float2*)(emb + (size_t)t * 128 + 2 * d2);
            ax += e.x; ay += e.y;
        }
    }
    float dn = 1.0f / fmaxf((float)cnt, 1.0f);
    ax = fmaxf(ax * dn, 0.f);
    ay = fmaxf(ay * dn, 0.f);
    u32 packed = ((u32)f2bf(ay) << 16) | (u32)f2bf(ax);
    if (n < Na) xa32[(size_t)n * 64 + d2] = packed;
    else        xp32[(size_t)(n - Na) * 64 + d2] = packed;
}

// ---------------------------------------------------------------------------
// Merged MFMA projection GEMM (both node types in one grid):
//  blocks [0, gba):        qa  = xa @ wqT          (ystride 128)
//  blocks [gba, gba+gbp):  ktmt[:, 0:128] = xp@wkaT, ktmt[:,128:256] = xp@wvmT
// Block = 4 waves; wave owns 16 rows x 128 cols. No LDS; W is L2-broadcast.
// D layout: col=lane&15, row=(lane>>4)*4+reg.
// ---------------------------------------------------------------------------
__global__ __launch_bounds__(256) void mfma_proj(
    const u16* __restrict__ xa, const u16* __restrict__ xp,
    const u16* __restrict__ wqT, const u16* __restrict__ wkaT,
    const u16* __restrict__ wvmT,
    u16* __restrict__ qa, u16* __restrict__ ktmt,
    int Na, int Np, int gba)
{
    int b = blockIdx.x;
    const u16 *A, *W0, *W1;
    u16 *Y0, *Y1;
    int N, ystride;
    if (b < gba) {
        A = xa; W0 = wqT; W1 = nullptr; Y0 = qa; Y1 = nullptr;
        N = Na; ystride = 128;
    } else {
        b -= gba;
        A = xp; W0 = wkaT; W1 = wvmT; Y0 = ktmt; Y1 = ktmt + 128;
        N = Np; ystride = 256;
    }
    int wave = threadIdx.x >> 6;
    int l = threadIdx.x & 63;
    int rbase = b * 64 + wave * 16;
    int arow = rbase + (l & 15);
    if (arow >= N) arow = N - 1;      // clamp; stores are guarded
    int kb = (l >> 4) * 8;

    bf16x8 af[4];
#pragma unroll
    for (int ks = 0; ks < 4; ++ks)
        af[ks] = *(const bf16x8*)(A + (size_t)arow * 128 + ks * 32 + kb);

    for (int w = 0; w < 2; ++w) {
        const u16* WT = w ? W1 : W0;
        u16* Y = w ? Y1 : Y0;
        if (!WT) break;
        f32x4 acc[8];
#pragma unroll
        for (int ct = 0; ct < 8; ++ct) acc[ct] = (f32x4){0.f, 0.f, 0.f, 0.f};
#pragma unroll
        for (int ks = 0; ks < 4; ++ks) {
#pragma unroll
            for (int ct = 0; ct < 8; ++ct) {
                bf16x8 bf = *(const bf16x8*)(WT + (size_t)(ct * 16 + (l & 15)) * 128 + ks * 32 + kb);
                acc[ct] = __builtin_amdgcn_mfma_f32_16x16x32_bf16(af[ks], bf, acc[ct], 0, 0, 0);
            }
        }
        int srow = rbase + ((l >> 4) << 2);
#pragma unroll
        for (int ct = 0; ct < 8; ++ct) {
            int col = ct * 16 + (l & 15);
#pragma unroll
            for (int r = 0; r < 4; ++r) {
                if (srow + r < N)
                    Y[(size_t)(srow + r) * ystride + col] = f2bf(acc[ct][r]);
            }
        }
    }
}

// ---------------------------------------------------------------------------
// MFMA output GEMM: out = A0@W0 + A1@W1 + bias  (bf16 in, f32 out)
// ---------------------------------------------------------------------------
__global__ __launch_bounds__(256) void mfma_out(
    const u16* __restrict__ A0, const u16* __restrict__ WT0,
    const u16* __restrict__ A1, const u16* __restrict__ WT1,
    const float* __restrict__ bias, float* __restrict__ Y, int N)
{
    int wave = threadIdx.x >> 6;
    int l = threadIdx.x & 63;
    int rbase = blockIdx.x * 64 + wave * 16;
    int arow = rbase + (l & 15);
    if (arow >= N) arow = N - 1;
    int kb = (l >> 4) * 8;

    f32x4 acc[8];
#pragma unroll
    for (int ct = 0; ct < 8; ++ct) acc[ct] = (f32x4){0.f, 0.f, 0.f, 0.f};

    for (int w = 0; w < 2; ++w) {
        const u16* A  = w ? A1 : A0;
        const u16* WT = w ? WT1 : WT0;
        bf16x8 af[4];
#pragma unroll
        for (int ks = 0; ks < 4; ++ks)
            af[ks] = *(const bf16x8*)(A + (size_t)arow * 128 + ks * 32 + kb);
#pragma unroll
        for (int ks = 0; ks < 4; ++ks) {
#pragma unroll
            for (int ct = 0; ct < 8; ++ct) {
                bf16x8 bf = *(const bf16x8*)(WT + (size_t)(ct * 16 + (l & 15)) * 128 + ks * 32 + kb);
                acc[ct] = __builtin_amdgcn_mfma_f32_16x16x32_bf16(af[ks], bf, acc[ct], 0, 0, 0);
            }
        }
    }
    int srow = rbase + ((l >> 4) << 2);
#pragma unroll
    for (int ct = 0; ct < 8; ++ct) {
        int col = ct * 16 + (l & 15);
        float b = bias[col];
#pragma unroll
        for (int r = 0; r < 4; ++r) {
            if (srow + r < N)
                Y[(size_t)(srow + r) * 128 + col] = acc[ct][r] + b;
        }
    }
}

// ---------------------------------------------------------------------------
// CSR build: histogram -> hierarchical scan (3 kernels) -> scatter
// ---------------------------------------------------------------------------
__global__ __launch_bounds__(256) void edge_hist(
    const int* __restrict__ dstI, int* __restrict__ deg, int E)
{
    int e = blockIdx.x * 256 + threadIdx.x;
    if (e < E) atomicAdd(&deg[dstI[e]], 1);
}

__global__ __launch_bounds__(256) void scan_local(
    const int* __restrict__ deg, int* __restrict__ locpref,
    int* __restrict__ blocksum, int Na)
{
    __shared__ int lds[256];
    int t = threadIdx.x;
    int base = blockIdx.x * 1024 + t * 4;
    int4 v = {0, 0, 0, 0};
    if (base + 3 < Na) {
        v = *(const int4*)(deg + base);
    } else {
        if (base + 0 < Na) v.x = deg[base + 0];
        if (base + 1 < Na) v.y = deg[base + 1];
        if (base + 2 < Na) v.z = deg[base + 2];
        if (base + 3 < Na) v.w = deg[base + 3];
    }
    int tot = v.x + v.y + v.z + v.w;
    lds[t] = tot;
    __syncthreads();
    for (int off = 1; off < 256; off <<= 1) {
        int u = (t >= off) ? lds[t - off] : 0;
        __syncthreads();
        lds[t] += u;
        __syncthreads();
    }
    int excl = lds[t] - tot;
    if (base < Na) {
        int4 o;
        o.x = excl;
        o.y = excl + v.x;
        o.z = o.y + v.y;
        o.w = o.z + v.z;
        if (base + 3 < Na) *(int4*)(locpref + base) = o;
        else {
            locpref[base] = o.x;
            if (base + 1 < Na) locpref[base + 1] = o.y;
            if (base + 2 < Na) locpref[base + 2] = o.z;
        }
    }
    if (t == 255) blocksum[blockIdx.x] = lds[255];
}

__global__ __launch_bounds__(256) void scan_block(
    const int* __restrict__ blocksum, int* __restrict__ blockoff,
    int* __restrict__ rowptr, int nb, int Na)
{
    __shared__ int lds[256];
    int t = threadIdx.x;
    int s = (t < nb) ? blocksum[t] : 0;
    lds[t] = s;
    __syncthreads();
    for (int off = 1; off < 256; off <<= 1) {
        int u = (t >= off) ? lds[t - off] : 0;
        __syncthreads();
        lds[t] += u;
        __syncthreads();
    }
    if (t < nb) blockoff[t] = lds[t] - s;
    if (t == 255) rowptr[Na] = lds[255];
}

__global__ __launch_bounds__(256) void scan_final(
    const int* __restrict__ locpref, const int* __restrict__ blockoff,
    int* __restrict__ rowptr, int* __restrict__ cursor, int Na)
{
    int i = blockIdx.x * 256 + threadIdx.x;
    if (i < Na) {
        int v = locpref[i] + blockoff[i >> 10];
        rowptr[i] = v;
        cursor[i] = v;
    }
}

__global__ __launch_bounds__(256) void edge_scatter(
    const int* __restrict__ srcI, const int* __restrict__ dstI,
    int* __restrict__ cursor, int* __restrict__ csrc, int E)
{
    int e = blockIdx.x * 256 + threadIdx.x;
    if (e < E) {
        int pos = atomicAdd(&cursor[dstI[e]], 1);
        csrc[pos] = srcI[e];
    }
}

// ---------------------------------------------------------------------------
// CSR aggregation: one wave per destination, 4-edge unrolled pipeline.
// ktmt interleaved: node row = 128 u32 ([0:64)=kt packed, [64:128)=mt packed)
// -> each edge streams ONE contiguous 512 B region.
// Softmax num/denom in registers; one 256 B store (normalize+gelu) per node.
// lane -> elems {2l,2l+1}; head h = lane>>4; 16-lane xor-reduce per score.
// ---------------------------------------------------------------------------
__device__ inline float edge_ev(u32 kv, float2 qf, float muh) {
    float2 kf = bf2f2(kv);
    float p = kf.x * qf.x + kf.y * qf.y;
    p += __shfl_xor(p, 1, 16);
    p += __shfl_xor(p, 2, 16);
    p += __shfl_xor(p, 4, 16);
    p += __shfl_xor(p, 8, 16);
    return __expf(p * muh);
}

__global__ __launch_bounds__(256) void csr_agg(
    const u32* __restrict__ ktmt, const u32* __restrict__ qap,
    const int* __restrict__ rowptr, const int* __restrict__ csrc,
    const float* __restrict__ mu1, u32* __restrict__ gagg, int Na)
{
    int dst = blockIdx.x * 4 + (threadIdx.x >> 6);
    if (dst >= Na) return;
    int lane = threadIdx.x & 63;
    int h = lane >> 4;
    float muh = mu1[h] * 0.17677669529663689f;  // mu/sqrt(32)
    float2 qf = bf2f2(qap[(size_t)dst * 64 + lane]);

    float a0 = 0.f, a1 = 0.f, dsum = 0.f;
    int beg = rowptr[dst], end = rowptr[dst + 1];

    int i = beg;
    for (; i + 4 <= end; i += 4) {
        int s0 = csrc[i], s1 = csrc[i + 1], s2 = csrc[i + 2], s3 = csrc[i + 3];
        u32 kv0 = ktmt[(size_t)s0 * 128 + lane];
        u32 mv0 = ktmt[(size_t)s0 * 128 + 64 + lane];
        u32 kv1 = ktmt[(size_t)s1 * 128 + lane];
        u32 mv1 = ktmt[(size_t)s1 * 128 + 64 + lane];
        u32 kv2 = ktmt[(size_t)s2 * 128 + lane];
        u32 mv2 = ktmt[(size_t)s2 * 128 + 64 + lane];
        u32 kv3 = ktmt[(size_t)s3 * 128 + lane];
        u32 mv3 = ktmt[(size_t)s3 * 128 + 64 + lane];
        float e0 = edge_ev(kv0, qf, muh);
        float e1 = edge_ev(kv1, qf, muh);
        float e2 = edge_ev(kv2, qf, muh);
        float e3 = edge_ev(kv3, qf, muh);
        float2 m0 = bf2f2(mv0), m1 = bf2f2(mv1), m2 = bf2f2(mv2), m3 = bf2f2(mv3);
        dsum += (e0 + e1) + (e2 + e3);
        a0 += e0 * m0.x + e1 * m1.x + e2 * m2.x + e3 * m3.x;
        a1 += e0 * m0.y + e1 * m1.y + e2 * m2.y + e3 * m3.y;
    }
    for (; i < end; ++i) {
        int s0 = csrc[i];
        u32 kv0 = ktmt[(size_t)s0 * 128 + lane];
        u32 mv0 = ktmt[(size_t)s0 * 128 + 64 + lane];
        float e0 = edge_ev(kv0, qf, muh);
        float2 m0 = bf2f2(mv0);
        dsum += e0; a0 += e0 * m0.x; a1 += e0 * m0.y;
    }
    float dn = dsum + 1e-9f;
    a0 = gelu_t(a0 / dn);
    a1 = gelu_t(a1 / dn);
    gagg[(size_t)dst * 64 + lane] = ((u32)f2bf(a1) << 16) | (u32)f2bf(a0);
}

// ---------------------------------------------------------------------------
extern "C" void kernel_launch(void* const* d_in, const int* in_sizes, int n_in,
                              void* d_out, int out_size, void* d_ws, size_t ws_size,
                              hipStream_t stream)
{
    const int*   tok_a   = (const int*)d_in[0];
    const int*   tok_p   = (const int*)d_in[1];
    const int*   edge_pa = (const int*)d_in[3];
    const float* emb     = (const float*)d_in[4];
    const float* Wk      = (const float*)d_in[5];
    const float* Wq      = (const float*)d_in[6];
    const float* Wv      = (const float*)d_in[7];
    const float* Watt    = (const float*)d_in[8];
    const float* Wmsg    = (const float*)d_in[9];
    const float* mu      = (const float*)d_in[10];
    const float* Wout    = (const float*)d_in[11];
    const float* lin_w   = (const float*)d_in[12];
    const float* lin_b   = (const float*)d_in[13];

    int Na = in_sizes[0] / L;
    int Np = in_sizes[1] / L;
    int E  = in_sizes[3] / 2;
    float* out = (float*)d_out;

    // workspace layout (all segments 16B-aligned)
    u16* xa      = (u16*)d_ws;                      // Na*128 bf16
    u16* qa      = xa + (size_t)Na * 128;           // Na*128 bf16
    u16* ktmt    = qa + (size_t)Na * 128;           // Np*256 bf16 (kt|mt interleaved)
    u16* xp      = ktmt + (size_t)Np * 256;         // Np*128 bf16
    u16* gagg    = xp + (size_t)Np * 128;           // Na*128 bf16
    int* deg     = (int*)(gagg + (size_t)Na * 128); // Na
    int* locpref = deg + Na;                        // Na
    int* rowptr  = locpref + Na;                    // Na+2
    int* cursor  = rowptr + Na + 2;                 // Na
    int* csrc    = cursor + Na;                     // E
    int* blocksum= csrc + E;                        // 256
    int* blockoff= blocksum + 256;                  // 256
    u16* wkaT    = (u16*)(blockoff + 256);          // 16384 bf16 each
    u16* wvmT    = wkaT + 16384;
    u16* wqT     = wvmT + 16384;
    u16* w1T     = wqT + 16384;
    u16* lwT     = w1T + 16384;

    const int* e_src = edge_pa;
    const int* e_dst = edge_pa + E;

    // 1) weight folding + CSR build
    hipMemsetAsync(deg, 0, (size_t)Na * sizeof(int), stream);
    fold_weights<<<(5 * 16384) / 256, 256, 0, stream>>>(
        Wk + 16384, Wq, Wv + 16384, Watt + 4096, Wmsg + 4096, Wout, lin_w,
        wkaT, wvmT, wqT, w1T, lwT);
    int egrid = (E + 255) / 256;
    edge_hist<<<egrid, 256, 0, stream>>>(e_dst, deg, E);
    int nb = (Na + 1023) / 1024;   // <= 256
    scan_local<<<nb, 256, 0, stream>>>(deg, locpref, blocksum, Na);
    scan_block<<<1, 256, 0, stream>>>(blocksum, blockoff, rowptr, nb, Na);
    scan_final<<<(Na + 255) / 256, 256, 0, stream>>>(locpref, blockoff, rowptr, cursor, Na);
    edge_scatter<<<egrid, 256, 0, stream>>>(e_src, e_dst, cursor, csrc, E);

    // 2) merged node encoding (wave per node, packed u32 stores)
    int Ntot = Na + Np;
    encode_nodes<<<((size_t)Ntot * 64 + 255) / 256, 256, 0, stream>>>(
        tok_a, tok_p, emb, (u32*)xa, (u32*)xp, Na, Ntot);

    // 3) merged MFMA projections
    int gba = (Na + 63) / 64;
    int gbp = (Np + 63) / 64;
    mfma_proj<<<gba + gbp, 256, 0, stream>>>(xa, xp, wqT, wkaT, wvmT,
                                             qa, ktmt, Na, Np, gba);

    // 4) CSR aggregation (softmax + weighted sum + normalize + gelu)
    csr_agg<<<(Na + 3) / 4, 256, 0, stream>>>(
        (const u32*)ktmt, (const u32*)qa, rowptr, csrc, mu + 4, (u32*)gagg, Na);

    // 5) output head: out = gagg@w1T + xa@lwT + lin_b
    mfma_out<<<gba, 256, 0, stream>>>(gagg, w1T, xa, lwT, lin_b, out, Na);
}

// Round 7
// 296.544 us; speedup vs baseline: 3.2950x; 1.0646x over previous
//
#include <hip/hip_runtime.h>
#include <math.h>

#define L 8

typedef unsigned int  u32;
typedef unsigned short u16;
typedef __attribute__((ext_vector_type(8))) short bf16x8;
typedef __attribute__((ext_vector_type(4))) float f32x4;

// fp32 -> bf16 round-to-nearest-even
__device__ inline u16 f2bf(float x) {
    u32 u = __float_as_uint(x);
    return (u16)((u + 0x7fffu + ((u >> 16) & 1u)) >> 16);
}
// unpack 2 packed bf16 (low = even elem, high = odd elem)
__device__ inline float2 bf2f2(u32 v) {
    float2 r;
    r.x = __uint_as_float(v << 16);
    r.y = __uint_as_float(v & 0xffff0000u);
    return r;
}
__device__ inline float gelu_t(float x) {
    return 0.5f * x * (1.0f + tanhf(0.7978845608028654f *
           (x + 0.044715f * x * x * x)));
}

// ---------------------------------------------------------------------------
// Convert fp32 embedding table -> packed bf16 (2.56 MB: fits per-XCD L2).
// Thread = 2 dims: float2 load, packed u32 store.
// ---------------------------------------------------------------------------
__global__ __launch_bounds__(256) void conv_emb(
    const float* __restrict__ emb, u32* __restrict__ emb_bf, int n2)
{
    int i = blockIdx.x * 256 + threadIdx.x;
    if (i >= n2) return;
    float2 e = *(const float2*)(emb + (size_t)i * 2);
    emb_bf[i] = ((u32)f2bf(e.y) << 16) | (u32)f2bf(e.x);
}

// ---------------------------------------------------------------------------
// Fold weights -> bf16, stored transposed (WT[c*128+k] = W[k][c]):
//  0: wkaT = (Wk1 . Watt1)^T   1: wvmT = (Wv1 . Wmsg1)^T   2: wqT = Wq0^T
//  3: w1T  = (Wout0 . lin_w)^T 4: lwT  = lin_w^T
// ---------------------------------------------------------------------------
__global__ __launch_bounds__(256) void fold_weights(
    const float* __restrict__ Wk1, const float* __restrict__ Wq0,
    const float* __restrict__ Wv1, const float* __restrict__ Watt1,
    const float* __restrict__ Wmsg1, const float* __restrict__ Wout0,
    const float* __restrict__ lin_w,
    u16* __restrict__ wkaT, u16* __restrict__ wvmT,
    u16* __restrict__ wqT, u16* __restrict__ w1T, u16* __restrict__ lwT)
{
    int id = blockIdx.x * 256 + threadIdx.x;   // < 5*16384
    int which = id >> 14;
    int idx = id & 16383;
    int col = idx & 127;
    int k = idx >> 7;
    if (which == 0) {
        int h = col >> 5, f = col & 31;
        float s = 0.f;
        for (int d = 0; d < 32; ++d)
            s += Wk1[k * 128 + h * 32 + d] * Watt1[h * 1024 + d * 32 + f];
        wkaT[col * 128 + k] = f2bf(s);
    } else if (which == 1) {
        int h = col >> 5, f = col & 31;
        float s = 0.f;
        for (int d = 0; d < 32; ++d)
            s += Wv1[k * 128 + h * 32 + d] * Wmsg1[h * 1024 + d * 32 + f];
        wvmT[col * 128 + k] = f2bf(s);
    } else if (which == 2) {
        wqT[col * 128 + k] = f2bf(Wq0[k * 128 + col]);
    } else if (which == 3) {
        float s = 0.f;
        for (int d = 0; d < 128; ++d)
            s += Wout0[k * 128 + d] * lin_w[d * 128 + col];
        w1T[col * 128 + k] = f2bf(s);
    } else {
        lwT[col * 128 + k] = f2bf(lin_w[k * 128 + col]);
    }
}

// ---------------------------------------------------------------------------
// Merged node encoder (authors + papers in one grid), bf16 emb gathers.
// One WAVE per node; lane covers 2 adjacent dims (u32 gather, u32 store).
// ---------------------------------------------------------------------------
__global__ __launch_bounds__(256) void encode_nodes(
    const int* __restrict__ tok_a, const int* __restrict__ tok_p,
    const u32* __restrict__ emb_bf,
    u32* __restrict__ xa32, u32* __restrict__ xp32, int Na, int Ntot)
{
    int i = blockIdx.x * 256 + threadIdx.x;
    int n = i >> 6, d2 = i & 63;
    if (n >= Ntot) return;
    const int* tok = (n < Na) ? (tok_a + (size_t)n * L)
                              : (tok_p + (size_t)(n - Na) * L);
    float ax = 0.f, ay = 0.f;
    int cnt = 0;
#pragma unroll
    for (int l = 0; l < L; ++l) {
        int t = tok[l];
        if (t != 0) {
            cnt++;
            float2 e = bf2f2(emb_bf[(size_t)t * 64 + d2]);
            ax += e.x; ay += e.y;
        }
    }
    float dn = 1.0f / fmaxf((float)cnt, 1.0f);
    ax = fmaxf(ax * dn, 0.f);
    ay = fmaxf(ay * dn, 0.f);
    u32 packed = ((u32)f2bf(ay) << 16) | (u32)f2bf(ax);
    if (n < Na) xa32[(size_t)n * 64 + d2] = packed;
    else        xp32[(size_t)(n - Na) * 64 + d2] = packed;
}

// ---------------------------------------------------------------------------
// Merged MFMA projection GEMM (both node types in one grid):
//  blocks [0, gba):        qa  = xa @ wqT          (ystride 128)
//  blocks [gba, gba+gbp):  ktmt[:, 0:128] = xp@wkaT, ktmt[:,128:256] = xp@wvmT
// Block = 4 waves; wave owns 16 rows x 128 cols. No LDS; W is L2-broadcast.
// D layout: col=lane&15, row=(lane>>4)*4+reg.
// ---------------------------------------------------------------------------
__global__ __launch_bounds__(256) void mfma_proj(
    const u16* __restrict__ xa, const u16* __restrict__ xp,
    const u16* __restrict__ wqT, const u16* __restrict__ wkaT,
    const u16* __restrict__ wvmT,
    u16* __restrict__ qa, u16* __restrict__ ktmt,
    int Na, int Np, int gba)
{
    int b = blockIdx.x;
    const u16 *A, *W0, *W1;
    u16 *Y0, *Y1;
    int N, ystride;
    if (b < gba) {
        A = xa; W0 = wqT; W1 = nullptr; Y0 = qa; Y1 = nullptr;
        N = Na; ystride = 128;
    } else {
        b -= gba;
        A = xp; W0 = wkaT; W1 = wvmT; Y0 = ktmt; Y1 = ktmt + 128;
        N = Np; ystride = 256;
    }
    int wave = threadIdx.x >> 6;
    int l = threadIdx.x & 63;
    int rbase = b * 64 + wave * 16;
    int arow = rbase + (l & 15);
    if (arow >= N) arow = N - 1;      // clamp; stores are guarded
    int kb = (l >> 4) * 8;

    bf16x8 af[4];
#pragma unroll
    for (int ks = 0; ks < 4; ++ks)
        af[ks] = *(const bf16x8*)(A + (size_t)arow * 128 + ks * 32 + kb);

    for (int w = 0; w < 2; ++w) {
        const u16* WT = w ? W1 : W0;
        u16* Y = w ? Y1 : Y0;
        if (!WT) break;
        f32x4 acc[8];
#pragma unroll
        for (int ct = 0; ct < 8; ++ct) acc[ct] = (f32x4){0.f, 0.f, 0.f, 0.f};
#pragma unroll
        for (int ks = 0; ks < 4; ++ks) {
#pragma unroll
            for (int ct = 0; ct < 8; ++ct) {
                bf16x8 bf = *(const bf16x8*)(WT + (size_t)(ct * 16 + (l & 15)) * 128 + ks * 32 + kb);
                acc[ct] = __builtin_amdgcn_mfma_f32_16x16x32_bf16(af[ks], bf, acc[ct], 0, 0, 0);
            }
        }
        int srow = rbase + ((l >> 4) << 2);
#pragma unroll
        for (int ct = 0; ct < 8; ++ct) {
            int col = ct * 16 + (l & 15);
#pragma unroll
            for (int r = 0; r < 4; ++r) {
                if (srow + r < N)
                    Y[(size_t)(srow + r) * ystride + col] = f2bf(acc[ct][r]);
            }
        }
    }
}

// ---------------------------------------------------------------------------
// MFMA output GEMM: out = A0@W0 + A1@W1 + bias  (bf16 in, f32 out)
// ---------------------------------------------------------------------------
__global__ __launch_bounds__(256) void mfma_out(
    const u16* __restrict__ A0, const u16* __restrict__ WT0,
    const u16* __restrict__ A1, const u16* __restrict__ WT1,
    const float* __restrict__ bias, float* __restrict__ Y, int N)
{
    int wave = threadIdx.x >> 6;
    int l = threadIdx.x & 63;
    int rbase = blockIdx.x * 64 + wave * 16;
    int arow = rbase + (l & 15);
    if (arow >= N) arow = N - 1;
    int kb = (l >> 4) * 8;

    f32x4 acc[8];
#pragma unroll
    for (int ct = 0; ct < 8; ++ct) acc[ct] = (f32x4){0.f, 0.f, 0.f, 0.f};

    for (int w = 0; w < 2; ++w) {
        const u16* A  = w ? A1 : A0;
        const u16* WT = w ? WT1 : WT0;
        bf16x8 af[4];
#pragma unroll
        for (int ks = 0; ks < 4; ++ks)
            af[ks] = *(const bf16x8*)(A + (size_t)arow * 128 + ks * 32 + kb);
#pragma unroll
        for (int ks = 0; ks < 4; ++ks) {
#pragma unroll
            for (int ct = 0; ct < 8; ++ct) {
                bf16x8 bf = *(const bf16x8*)(WT + (size_t)(ct * 16 + (l & 15)) * 128 + ks * 32 + kb);
                acc[ct] = __builtin_amdgcn_mfma_f32_16x16x32_bf16(af[ks], bf, acc[ct], 0, 0, 0);
            }
        }
    }
    int srow = rbase + ((l >> 4) << 2);
#pragma unroll
    for (int ct = 0; ct < 8; ++ct) {
        int col = ct * 16 + (l & 15);
        float b = bias[col];
#pragma unroll
        for (int r = 0; r < 4; ++r) {
            if (srow + r < N)
                Y[(size_t)(srow + r) * 128 + col] = acc[ct][r] + b;
        }
    }
}

// ---------------------------------------------------------------------------
// CSR build: histogram -> hierarchical scan (3 kernels) -> scatter
// ---------------------------------------------------------------------------
__global__ __launch_bounds__(256) void edge_hist(
    const int* __restrict__ dstI, int* __restrict__ deg, int E)
{
    int e = blockIdx.x * 256 + threadIdx.x;
    if (e < E) atomicAdd(&deg[dstI[e]], 1);
}

__global__ __launch_bounds__(256) void scan_local(
    const int* __restrict__ deg, int* __restrict__ locpref,
    int* __restrict__ blocksum, int Na)
{
    __shared__ int lds[256];
    int t = threadIdx.x;
    int base = blockIdx.x * 1024 + t * 4;
    int4 v = {0, 0, 0, 0};
    if (base + 3 < Na) {
        v = *(const int4*)(deg + base);
    } else {
        if (base + 0 < Na) v.x = deg[base + 0];
        if (base + 1 < Na) v.y = deg[base + 1];
        if (base + 2 < Na) v.z = deg[base + 2];
        if (base + 3 < Na) v.w = deg[base + 3];
    }
    int tot = v.x + v.y + v.z + v.w;
    lds[t] = tot;
    __syncthreads();
    for (int off = 1; off < 256; off <<= 1) {
        int u = (t >= off) ? lds[t - off] : 0;
        __syncthreads();
        lds[t] += u;
        __syncthreads();
    }
    int excl = lds[t] - tot;
    if (base < Na) {
        int4 o;
        o.x = excl;
        o.y = excl + v.x;
        o.z = o.y + v.y;
        o.w = o.z + v.z;
        if (base + 3 < Na) *(int4*)(locpref + base) = o;
        else {
            locpref[base] = o.x;
            if (base + 1 < Na) locpref[base + 1] = o.y;
            if (base + 2 < Na) locpref[base + 2] = o.z;
        }
    }
    if (t == 255) blocksum[blockIdx.x] = lds[255];
}

__global__ __launch_bounds__(256) void scan_block(
    const int* __restrict__ blocksum, int* __restrict__ blockoff,
    int* __restrict__ rowptr, int nb, int Na)
{
    __shared__ int lds[256];
    int t = threadIdx.x;
    int s = (t < nb) ? blocksum[t] : 0;
    lds[t] = s;
    __syncthreads();
    for (int off = 1; off < 256; off <<= 1) {
        int u = (t >= off) ? lds[t - off] : 0;
        __syncthreads();
        lds[t] += u;
        __syncthreads();
    }
    if (t < nb) blockoff[t] = lds[t] - s;
    if (t == 255) rowptr[Na] = lds[255];
}

__global__ __launch_bounds__(256) void scan_final(
    const int* __restrict__ locpref, const int* __restrict__ blockoff,
    int* __restrict__ rowptr, int* __restrict__ cursor, int Na)
{
    int i = blockIdx.x * 256 + threadIdx.x;
    if (i < Na) {
        int v = locpref[i] + blockoff[i >> 10];
        rowptr[i] = v;
        cursor[i] = v;
    }
}

__global__ __launch_bounds__(256) void edge_scatter(
    const int* __restrict__ srcI, const int* __restrict__ dstI,
    int* __restrict__ cursor, int* __restrict__ csrc, int E)
{
    int e = blockIdx.x * 256 + threadIdx.x;
    if (e < E) {
        int pos = atomicAdd(&cursor[dstI[e]], 1);
        csrc[pos] = srcI[e];
    }
}

// ---------------------------------------------------------------------------
// CSR aggregation: one wave per destination, 4-edge unrolled pipeline.
// ktmt interleaved: node row = 128 u32 ([0:64)=kt packed, [64:128)=mt packed)
// -> each edge streams ONE contiguous 512 B region.
// Softmax num/denom in registers; one 256 B store (normalize+gelu) per node.
// lane -> elems {2l,2l+1}; head h = lane>>4; 16-lane xor-reduce per score.
// ---------------------------------------------------------------------------
__device__ inline float edge_ev(u32 kv, float2 qf, float muh) {
    float2 kf = bf2f2(kv);
    float p = kf.x * qf.x + kf.y * qf.y;
    p += __shfl_xor(p, 1, 16);
    p += __shfl_xor(p, 2, 16);
    p += __shfl_xor(p, 4, 16);
    p += __shfl_xor(p, 8, 16);
    return __expf(p * muh);
}

__global__ __launch_bounds__(256) void csr_agg(
    const u32* __restrict__ ktmt, const u32* __restrict__ qap,
    const int* __restrict__ rowptr, const int* __restrict__ csrc,
    const float* __restrict__ mu1, u32* __restrict__ gagg, int Na)
{
    int dst = blockIdx.x * 4 + (threadIdx.x >> 6);
    if (dst >= Na) return;
    int lane = threadIdx.x & 63;
    int h = lane >> 4;
    float muh = mu1[h] * 0.17677669529663689f;  // mu/sqrt(32)
    float2 qf = bf2f2(qap[(size_t)dst * 64 + lane]);

    float a0 = 0.f, a1 = 0.f, dsum = 0.f;
    int beg = rowptr[dst], end = rowptr[dst + 1];

    int i = beg;
    for (; i + 4 <= end; i += 4) {
        int s0 = csrc[i], s1 = csrc[i + 1], s2 = csrc[i + 2], s3 = csrc[i + 3];
        u32 kv0 = ktmt[(size_t)s0 * 128 + lane];
        u32 mv0 = ktmt[(size_t)s0 * 128 + 64 + lane];
        u32 kv1 = ktmt[(size_t)s1 * 128 + lane];
        u32 mv1 = ktmt[(size_t)s1 * 128 + 64 + lane];
        u32 kv2 = ktmt[(size_t)s2 * 128 + lane];
        u32 mv2 = ktmt[(size_t)s2 * 128 + 64 + lane];
        u32 kv3 = ktmt[(size_t)s3 * 128 + lane];
        u32 mv3 = ktmt[(size_t)s3 * 128 + 64 + lane];
        float e0 = edge_ev(kv0, qf, muh);
        float e1 = edge_ev(kv1, qf, muh);
        float e2 = edge_ev(kv2, qf, muh);
        float e3 = edge_ev(kv3, qf, muh);
        float2 m0 = bf2f2(mv0), m1 = bf2f2(mv1), m2 = bf2f2(mv2), m3 = bf2f2(mv3);
        dsum += (e0 + e1) + (e2 + e3);
        a0 += e0 * m0.x + e1 * m1.x + e2 * m2.x + e3 * m3.x;
        a1 += e0 * m0.y + e1 * m1.y + e2 * m2.y + e3 * m3.y;
    }
    for (; i < end; ++i) {
        int s0 = csrc[i];
        u32 kv0 = ktmt[(size_t)s0 * 128 + lane];
        u32 mv0 = ktmt[(size_t)s0 * 128 + 64 + lane];
        float e0 = edge_ev(kv0, qf, muh);
        float2 m0 = bf2f2(mv0);
        dsum += e0; a0 += e0 * m0.x; a1 += e0 * m0.y;
    }
    float dn = dsum + 1e-9f;
    a0 = gelu_t(a0 / dn);
    a1 = gelu_t(a1 / dn);
    gagg[(size_t)dst * 64 + lane] = ((u32)f2bf(a1) << 16) | (u32)f2bf(a0);
}

// ---------------------------------------------------------------------------
extern "C" void kernel_launch(void* const* d_in, const int* in_sizes, int n_in,
                              void* d_out, int out_size, void* d_ws, size_t ws_size,
                              hipStream_t stream)
{
    const int*   tok_a   = (const int*)d_in[0];
    const int*   tok_p   = (const int*)d_in[1];
    const int*   edge_pa = (const int*)d_in[3];
    const float* emb     = (const float*)d_in[4];
    const float* Wk      = (const float*)d_in[5];
    const float* Wq      = (const float*)d_in[6];
    const float* Wv      = (const float*)d_in[7];
    const float* Watt    = (const float*)d_in[8];
    const float* Wmsg    = (const float*)d_in[9];
    const float* mu      = (const float*)d_in[10];
    const float* Wout    = (const float*)d_in[11];
    const float* lin_w   = (const float*)d_in[12];
    const float* lin_b   = (const float*)d_in[13];

    int Na = in_sizes[0] / L;
    int Np = in_sizes[1] / L;
    int E  = in_sizes[3] / 2;
    int V  = in_sizes[4] / 128;
    float* out = (float*)d_out;

    // workspace layout (all segments 16B-aligned)
    u16* xa      = (u16*)d_ws;                      // Na*128 bf16
    u16* qa      = xa + (size_t)Na * 128;           // Na*128 bf16
    u16* ktmt    = qa + (size_t)Na * 128;           // Np*256 bf16 (kt|mt interleaved)
    u16* xp      = ktmt + (size_t)Np * 256;         // Np*128 bf16
    u16* gagg    = xp + (size_t)Np * 128;           // Na*128 bf16
    u16* emb_bf  = gagg + (size_t)Na * 128;         // V*128 bf16
    int* deg     = (int*)(emb_bf + (size_t)V * 128);// Na
    int* locpref = deg + Na;                        // Na
    int* rowptr  = locpref + Na;                    // Na+2
    int* cursor  = rowptr + Na + 2;                 // Na
    int* csrc    = cursor + Na;                     // E
    int* blocksum= csrc + E;                        // 256
    int* blockoff= blocksum + 256;                  // 256
    u16* wkaT    = (u16*)(blockoff + 256);          // 16384 bf16 each
    u16* wvmT    = wkaT + 16384;
    u16* wqT     = wvmT + 16384;
    u16* w1T     = wqT + 16384;
    u16* lwT     = w1T + 16384;

    const int* e_src = edge_pa;
    const int* e_dst = edge_pa + E;

    // 1) emb conversion + weight folding + CSR build
    hipMemsetAsync(deg, 0, (size_t)Na * sizeof(int), stream);
    conv_emb<<<((size_t)V * 64 + 255) / 256, 256, 0, stream>>>(
        emb, (u32*)emb_bf, V * 64);
    fold_weights<<<(5 * 16384) / 256, 256, 0, stream>>>(
        Wk + 16384, Wq, Wv + 16384, Watt + 4096, Wmsg + 4096, Wout, lin_w,
        wkaT, wvmT, wqT, w1T, lwT);
    int egrid = (E + 255) / 256;
    edge_hist<<<egrid, 256, 0, stream>>>(e_dst, deg, E);
    int nb = (Na + 1023) / 1024;   // <= 256
    scan_local<<<nb, 256, 0, stream>>>(deg, locpref, blocksum, Na);
    scan_block<<<1, 256, 0, stream>>>(blocksum, blockoff, rowptr, nb, Na);
    scan_final<<<(Na + 255) / 256, 256, 0, stream>>>(locpref, blockoff, rowptr, cursor, Na);
    edge_scatter<<<egrid, 256, 0, stream>>>(e_src, e_dst, cursor, csrc, E);

    // 2) merged node encoding (wave per node, bf16 emb gathers, u32 stores)
    int Ntot = Na + Np;
    encode_nodes<<<((size_t)Ntot * 64 + 255) / 256, 256, 0, stream>>>(
        tok_a, tok_p, (const u32*)emb_bf, (u32*)xa, (u32*)xp, Na, Ntot);

    // 3) merged MFMA projections
    int gba = (Na + 63) / 64;
    int gbp = (Np + 63) / 64;
    mfma_proj<<<gba + gbp, 256, 0, stream>>>(xa, xp, wqT, wkaT, wvmT,
                                             qa, ktmt, Na, Np, gba);

    // 4) CSR aggregation (softmax + weighted sum + normalize + gelu)
    csr_agg<<<(Na + 3) / 4, 256, 0, stream>>>(
        (const u32*)ktmt, (const u32*)qa, rowptr, csrc, mu + 4, (u32*)gagg, Na);

    // 5) output head: out = gagg@w1T + xa@lwT + lin_b
    mfma_out<<<gba, 256, 0, stream>>>(gagg, w1T, xa, lwT, lin_b, out, Na);
}